// Round 3
// baseline (3777.688 us; speedup 1.0000x reference)
//
#include <hip/hip_runtime.h>
#include <hip/hip_bf16.h>
#include <math.h>

#define NTOT   32768
#define NPER   4096
#define NGRAPH 8
#define EDGES  262144
#define HCH    128
#define EPSBN  1e-5f

typedef short bf16x8 __attribute__((ext_vector_type(8)));
typedef float f32x4  __attribute__((ext_vector_type(4)));

__device__ __forceinline__ float eluf(float x){ return x > 0.f ? x : expm1f(x); }
__device__ __forceinline__ ushort f2bf(float f){
    uint u = __float_as_uint(f);
    u += 0x7fffu + ((u >> 16) & 1u);          // round-to-nearest-even
    return (ushort)(u >> 16);
}
__device__ __forceinline__ float bfhi(uint p){ return __uint_as_float(p & 0xffff0000u); }
__device__ __forceinline__ float bflo(uint p){ return __uint_as_float(p << 16); }
__device__ __forceinline__ uint packu(float v){
    ushort hi = f2bf(v);
    float r = v - __uint_as_float(((uint)hi) << 16);
    ushort lo = f2bf(r);
    return (((uint)hi) << 16) | (uint)lo;
}

// ---------------- CSR build ----------------
__global__ __launch_bounds__(256) void k_hist(const int* __restrict__ dst, int* __restrict__ deg){
    int e = blockIdx.x * 256 + threadIdx.x;
    atomicAdd(&deg[dst[e]], 1);
}

__global__ __launch_bounds__(1024) void k_scan(const int* __restrict__ deg, int* __restrict__ rowptr,
                                               int* __restrict__ cursor){
    __shared__ int part[1024];
    int t = threadIdx.x;
    const int chunk = NTOT / 1024;
    int base = t * chunk;
    int s = 0;
    for (int j = 0; j < chunk; ++j) s += deg[base + j];
    part[t] = s; __syncthreads();
    for (int off = 1; off < 1024; off <<= 1){
        int v = (t >= off) ? part[t - off] : 0;
        __syncthreads();
        part[t] += v;
        __syncthreads();
    }
    int run = part[t] - s;
    for (int j = 0; j < chunk; ++j){
        rowptr[base + j] = run; cursor[base + j] = run;
        run += deg[base + j];
    }
    if (t == 1023) rowptr[NTOT] = run;
}

__global__ __launch_bounds__(256) void k_scatter(const int* __restrict__ src, const int* __restrict__ dst,
                                                 const float* __restrict__ L, int* __restrict__ cursor,
                                                 int* __restrict__ esrc, float* __restrict__ ew){
    int e = blockIdx.x * 256 + threadIdx.x;
    int d = dst[e];
    int pos = atomicAdd(&cursor[d], 1);
    esrc[pos] = src[e];
    ew[pos]   = L[e];
}

// ---------------- per-graph mask count ----------------
__global__ __launch_bounds__(256) void k_cnt(const float* __restrict__ mask, float* __restrict__ gcnt){
    __shared__ float red[4];
    int g = blockIdx.x, t = threadIdx.x;
    float s = 0.f;
    for (int i = t; i < NPER; i += 256) s += mask[g * NPER + i];
    #pragma unroll
    for (int off = 32; off > 0; off >>= 1) s += __shfl_down(s, off);
    if ((t & 63) == 0) red[t >> 6] = s;
    __syncthreads();
    if (t == 0) gcnt[g] = red[0] + red[1] + red[2] + red[3];
}

// ---------------- conv1: H = x@W1+b1 ; Upk = pack(elu(H)) ; stats ----------------
__global__ __launch_bounds__(256) void k_conv1(const float* __restrict__ x, const float* __restrict__ W1,
                                               const float* __restrict__ b1, float* __restrict__ H,
                                               uint* __restrict__ Upk, float* __restrict__ sums0){
    __shared__ float red[2][2][128];
    int t = threadIdx.x, ch = t & 127, pr = t >> 7;
    float w0 = W1[ch], w1 = W1[128 + ch], w2 = W1[256 + ch], bv = b1[ch];
    int base = blockIdx.x * 128;
    float ls = 0.f, lss = 0.f;
    for (int it = 0; it < 64; ++it){
        int row = base + 2 * it + pr;
        const float* xr = x + (size_t)row * 3;
        float h = fmaf(xr[2], w2, fmaf(xr[1], w1, fmaf(xr[0], w0, bv)));
        H[(size_t)row * HCH + ch] = h;
        float u = eluf(h);
        Upk[(size_t)row * HCH + ch] = packu(u);
        ls += u; lss += u * u;
    }
    red[0][pr][ch] = ls; red[1][pr][ch] = lss;
    __syncthreads();
    if (t < 128){
        atomicAdd(&sums0[t],       red[0][0][t] + red[0][1][t]);
        atomicAdd(&sums0[256 + t], red[1][0][t] + red[1][1][t]);
    }
}

// ---------------- SpMM (CSR by dst), hi-only gather, packed output + BN stats ----------------
__global__ __launch_bounds__(256) void k_spmm(const uint* __restrict__ Upk, const int* __restrict__ rowptr,
                                              const int* __restrict__ esrc, const float* __restrict__ ew,
                                              uint* __restrict__ AGG, float* __restrict__ sums_k){
    __shared__ float red[2][8][128];
    const int t = threadIdx.x;
    const int nl = t >> 5;
    const int c4 = (t & 31) << 2;
    const int bid = blockIdx.x;
    const int sb = ((bid & 7) << 9) | (bid >> 3);   // graph g -> XCD g
    const int node = sb * 8 + nl;
    const int e0 = rowptr[node], e1 = rowptr[node + 1];
    float4 a = {0,0,0,0};
    int e = e0;
    for (; e + 4 <= e1; e += 4){
        int   s0 = esrc[e],   s1 = esrc[e+1], s2 = esrc[e+2], s3 = esrc[e+3];
        float w0 = ew[e],     w1 = ew[e+1],   w2 = ew[e+2],   w3 = ew[e+3];
        uint4 p0 = *(const uint4*)(Upk + (size_t)s0 * HCH + c4);
        uint4 p1 = *(const uint4*)(Upk + (size_t)s1 * HCH + c4);
        uint4 p2 = *(const uint4*)(Upk + (size_t)s2 * HCH + c4);
        uint4 p3 = *(const uint4*)(Upk + (size_t)s3 * HCH + c4);
        a.x=fmaf(bfhi(p0.x),w0,a.x); a.y=fmaf(bfhi(p0.y),w0,a.y); a.z=fmaf(bfhi(p0.z),w0,a.z); a.w=fmaf(bfhi(p0.w),w0,a.w);
        a.x=fmaf(bfhi(p1.x),w1,a.x); a.y=fmaf(bfhi(p1.y),w1,a.y); a.z=fmaf(bfhi(p1.z),w1,a.z); a.w=fmaf(bfhi(p1.w),w1,a.w);
        a.x=fmaf(bfhi(p2.x),w2,a.x); a.y=fmaf(bfhi(p2.y),w2,a.y); a.z=fmaf(bfhi(p2.z),w2,a.z); a.w=fmaf(bfhi(p2.w),w2,a.w);
        a.x=fmaf(bfhi(p3.x),w3,a.x); a.y=fmaf(bfhi(p3.y),w3,a.y); a.z=fmaf(bfhi(p3.z),w3,a.z); a.w=fmaf(bfhi(p3.w),w3,a.w);
    }
    for (; e < e1; ++e){
        int s0 = esrc[e]; float w0 = ew[e];
        uint4 p0 = *(const uint4*)(Upk + (size_t)s0 * HCH + c4);
        a.x=fmaf(bfhi(p0.x),w0,a.x); a.y=fmaf(bfhi(p0.y),w0,a.y); a.z=fmaf(bfhi(p0.z),w0,a.z); a.w=fmaf(bfhi(p0.w),w0,a.w);
    }
    uint4 o;
    o.x = packu(a.x); o.y = packu(a.y); o.z = packu(a.z); o.w = packu(a.w);
    *(uint4*)(AGG + (size_t)node * HCH + c4) = o;

    red[0][nl][c4+0]=a.x;     red[0][nl][c4+1]=a.y;     red[0][nl][c4+2]=a.z;     red[0][nl][c4+3]=a.w;
    red[1][nl][c4+0]=a.x*a.x; red[1][nl][c4+1]=a.y*a.y; red[1][nl][c4+2]=a.z*a.z; red[1][nl][c4+3]=a.w*a.w;
    __syncthreads();
    if (t < 128){
        float s = 0.f, q = 0.f;
        #pragma unroll
        for (int n2 = 0; n2 < 8; ++n2){ s += red[0][n2][t]; q += red[1][n2][t]; }
        atomicAdd(&sums_k[128 + t], s);
        atomicAdd(&sums_k[384 + t], q);
    }
}

// ---------------- per-layer weight prep: W' = s*W (split hi/lo, transposed), b' = shift@W + b ----------------
template<int MODE>
__global__ __launch_bounds__(256) void k_prep(
        const float* __restrict__ W, const float* __restrict__ bias,
        const float* __restrict__ gamma, const float* __restrict__ beta,
        const float* __restrict__ sums_k, const float* __restrict__ gsum_k,
        const float* __restrict__ gcnt,
        ushort* __restrict__ Whi, ushort* __restrict__ Wlo, float* __restrict__ bprm)
{
    constexpr int KW = MODE ? 128 : 256;
    __shared__ float s_s[256], s_sh[256];
    __shared__ float s_avg[NGRAPH * 128];
    const int t = threadIdx.x;
    {
        float m, ex2;
        if (MODE == 1 && t >= 128){
            float S1 = 0.f, S2 = 0.f;
            #pragma unroll
            for (int g = 0; g < NGRAPH; ++g){
                float a = gsum_k[g * 128 + (t - 128)] / gcnt[g];
                s_avg[g * 128 + (t - 128)] = a;
                S1 += a; S2 += a * a;
            }
            m = S1 * (1.f / NGRAPH); ex2 = S2 * (1.f / NGRAPH);
        } else {
            m   = sums_k[t]       * (1.f / NTOT);
            ex2 = sums_k[256 + t] * (1.f / NTOT);
        }
        float var = ex2 - m * m;
        float sc = gamma[t] * rsqrtf(var + EPSBN);
        s_s[t] = sc; s_sh[t] = beta[t] - m * sc;
    }
    __syncthreads();
    if (blockIdx.x < 8){
        const int rows = KW / 8;
        const int c0 = blockIdx.x * rows;
        for (int idx = t; idx < rows * 128; idx += 256){
            int c = c0 + (idx >> 7), n = idx & 127;
            float v = W[(size_t)c * 128 + n] * s_s[c];
            ushort hi = f2bf(v);
            ushort lo = f2bf(v - __uint_as_float(((uint)hi) << 16));
            Whi[(size_t)n * KW + c] = hi;
            Wlo[(size_t)n * KW + c] = lo;
        }
    } else if (t < 128){
        const int n = t;
        float acc = bias[n];
        if (MODE == 0){
            for (int c = 0; c < 256; ++c) acc = fmaf(s_sh[c], W[(size_t)c * 128 + n], acc);
            bprm[n] = acc;
        } else {
            for (int c = 0; c < 128; ++c) acc = fmaf(s_sh[c], W[(size_t)c * 128 + n], acc);
            for (int g = 0; g < NGRAPH; ++g){
                float bg = acc;
                for (int c = 0; c < 128; ++c)
                    bg = fmaf(fmaf(s_avg[g * 128 + c], s_s[128 + c], s_sh[128 + c]),
                              W[(size_t)(128 + c) * 128 + n], bg);
                bprm[g * 128 + n] = bg;
            }
        }
    }
}

// ---------------- MFMA GEMM (bf16x3) + bias (+residual) + ELU + pack + next-layer stats ----------------
template<int MODE, int RES>
__global__ __launch_bounds__(256) void k_gemm(
        const uint* __restrict__ Upk, const uint* __restrict__ AGG,
        const ushort* __restrict__ Whi, const ushort* __restrict__ Wlo,
        const float* __restrict__ bprm,
        const float* __restrict__ Hres, float* __restrict__ Hout,
        uint* __restrict__ Uout, float* __restrict__ sums_n,
        const float* __restrict__ mask, float* __restrict__ gsum_next)
{
    constexpr int KC = (MODE == 0) ? 8 : 4;     // k-chunks of 32
    constexpr int KW = KC * 32;                 // W' row length
    __shared__ float red[2][16][128];
    const int t = threadIdx.x;
    const int w = t >> 6, lane = t & 63;
    const int rlo = lane & 15, kg = lane >> 4;
    const int bid = blockIdx.x;
    const int sb  = ((bid & 7) << 6) | (bid >> 3);   // graph g -> XCD g
    const int row0 = sb * 64;
    const int arow = row0 + w * 16 + rlo;

    f32x4 acc[8];
    #pragma unroll
    for (int n = 0; n < 8; ++n) acc[n] = (f32x4){0.f, 0.f, 0.f, 0.f};

    #pragma unroll
    for (int kc = 0; kc < KC; ++kc){
        const uint* ap = (MODE == 0 && kc >= 4)
                       ? (AGG + (size_t)arow * 128 + (kc - 4) * 32 + kg * 8)
                       : (Upk + (size_t)arow * 128 + kc * 32 + kg * 8);
        uint4 p0 = *(const uint4*)(ap);
        uint4 p1 = *(const uint4*)(ap + 4);
        union { uint u[4]; bf16x8 v; } ah, al;
        ah.u[0] = (p0.x >> 16) | (p0.y & 0xffff0000u);
        ah.u[1] = (p0.z >> 16) | (p0.w & 0xffff0000u);
        ah.u[2] = (p1.x >> 16) | (p1.y & 0xffff0000u);
        ah.u[3] = (p1.z >> 16) | (p1.w & 0xffff0000u);
        al.u[0] = (p0.x & 0xffffu) | (p0.y << 16);
        al.u[1] = (p0.z & 0xffffu) | (p0.w << 16);
        al.u[2] = (p1.x & 0xffffu) | (p1.y << 16);
        al.u[3] = (p1.z & 0xffffu) | (p1.w << 16);
        const int kb = kc * 32 + kg * 8;
        #pragma unroll
        for (int n = 0; n < 8; ++n){
            bf16x8 bh = *(const bf16x8*)(Whi + (size_t)(n * 16 + rlo) * KW + kb);
            bf16x8 bl = *(const bf16x8*)(Wlo + (size_t)(n * 16 + rlo) * KW + kb);
            acc[n] = __builtin_amdgcn_mfma_f32_16x16x32_bf16(ah.v, bh, acc[n], 0, 0, 0);
            acc[n] = __builtin_amdgcn_mfma_f32_16x16x32_bf16(ah.v, bl, acc[n], 0, 0, 0);
            acc[n] = __builtin_amdgcn_mfma_f32_16x16x32_bf16(al.v, bh, acc[n], 0, 0, 0);
        }
    }

    // epilogue
    const float* bp = (MODE == 1) ? (bprm + (row0 >> 12) * 128) : bprm;
    const int r0 = row0 + w * 16 + kg * 4;
    float mk0 = 0.f, mk1 = 0.f, mk2 = 0.f, mk3 = 0.f;
    if (gsum_next){ mk0 = mask[r0]; mk1 = mask[r0+1]; mk2 = mask[r0+2]; mk3 = mask[r0+3]; }
    float sN[8], qN[8], gN[8];
    #pragma unroll
    for (int n = 0; n < 8; ++n){
        const int c = n * 16 + rlo;
        const float bc = bp[c];
        float s = 0.f, q = 0.f, g = 0.f;
        #pragma unroll
        for (int r = 0; r < 4; ++r){
            int row = r0 + r;
            float h = acc[n][r] + bc;
            if (RES){
                h += Hres[(size_t)row * HCH + c];
                Hout[(size_t)row * HCH + c] = h;
            }
            float u = eluf(h);
            Uout[(size_t)row * HCH + c] = packu(u);
            s += u; q += u * u;
            if (gsum_next){
                float mkr = (r == 0) ? mk0 : (r == 1) ? mk1 : (r == 2) ? mk2 : mk3;
                g = fmaf(u, mkr, g);
            }
        }
        sN[n] = s; qN[n] = q; gN[n] = g;
    }
    const int slot = w * 4 + kg;
    #pragma unroll
    for (int n = 0; n < 8; ++n){
        red[0][slot][n * 16 + rlo] = sN[n];
        red[1][slot][n * 16 + rlo] = qN[n];
    }
    __syncthreads();
    if (t < 128){
        float a = 0.f, b = 0.f;
        #pragma unroll
        for (int q = 0; q < 16; ++q){ a += red[0][q][t]; b += red[1][q][t]; }
        atomicAdd(&sums_n[t], a);
        atomicAdd(&sums_n[256 + t], b);
    }
    if (gsum_next){
        __syncthreads();
        #pragma unroll
        for (int n = 0; n < 8; ++n) red[0][slot][n * 16 + rlo] = gN[n];
        __syncthreads();
        if (t < 128){
            float a = 0.f;
            #pragma unroll
            for (int q = 0; q < 16; ++q) a += red[0][q][t];
            atomicAdd(&gsum_next[(row0 >> 12) * 128 + t], a);
        }
    }
}

// ---------------- final: BN(elu(h)) @ W2 + b2 + x[:, :1] ----------------
__global__ __launch_bounds__(256) void k_final(const uint* __restrict__ Upk, const float* __restrict__ sums30,
                                               const float* __restrict__ g2, const float* __restrict__ beta2,
                                               const float* __restrict__ W2, const float* __restrict__ b2,
                                               const float* __restrict__ x, float* __restrict__ out){
    __shared__ float s_s[128], s_sh[128];
    __shared__ float wred[4];
    int t = threadIdx.x;
    if (t < 128){
        float m   = sums30[t]       * (1.f / NTOT);
        float ex2 = sums30[256 + t] * (1.f / NTOT);
        float var = ex2 - m * m;
        float sc = g2[t] * rsqrtf(var + EPSBN);
        s_s[t] = sc; s_sh[t] = beta2[t] - m * sc;
    }
    __syncthreads();
    int lane = t & 63, wid = t >> 6;
    int ch = t & 127, pr = t >> 7;
    float w2 = W2[ch];
    float b2v = b2[0];
    int base = blockIdx.x * 64;
    for (int it = 0; it < 32; ++it){
        int rowa = base + it * 2;
        int row  = rowa + pr;
        uint p = Upk[(size_t)row * HCH + ch];
        float u = bfhi(p) + bflo(p);
        float v = (u * s_s[ch] + s_sh[ch]) * w2;
        #pragma unroll
        for (int off = 32; off > 0; off >>= 1) v += __shfl_down(v, off);
        if (lane == 0) wred[wid] = v;
        __syncthreads();
        if (t == 0)   out[rowa]     = wred[0] + wred[1] + b2v + x[(size_t)rowa * 3];
        if (t == 128) out[rowa + 1] = wred[2] + wred[3] + b2v + x[(size_t)(rowa + 1) * 3];
        __syncthreads();
    }
}

// ---------------- host ----------------
extern "C" void kernel_launch(void* const* d_in, const int* in_sizes, int n_in,
                              void* d_out, int out_size, void* d_ws, size_t ws_size,
                              hipStream_t stream){
    const float* x    = (const float*)d_in[0];
    const float* L    = (const float*)d_in[1];
    const float* mask = (const float*)d_in[2];
    const float* W1   = (const float*)d_in[3];
    const float* b1   = (const float*)d_in[4];
    const float* Wb   = (const float*)d_in[5];
    const float* bb   = (const float*)d_in[6];
    const float* gb   = (const float*)d_in[7];
    const float* betab= (const float*)d_in[8];
    const float* g2   = (const float*)d_in[9];
    const float* beta2= (const float*)d_in[10];
    const float* W2   = (const float*)d_in[11];
    const float* b2   = (const float*)d_in[12];
    const int*   src  = (const int*)d_in[13];
    const int*   dst  = (const int*)d_in[14];

    char* base = (char*)d_ws;
    size_t off = 0;
    auto alloc = [&](size_t bytes)->char*{
        char* r = base + off;
        off = (off + bytes + 255) & ~(size_t)255;
        return r;
    };
    float* sums  = (float*)alloc(31 * 512 * sizeof(float));
    float* gsum  = (float*)alloc(30 * NGRAPH * HCH * sizeof(float));
    int*   deg   = (int*)  alloc(NTOT * sizeof(int));
    size_t zero_bytes = off;                                       // zeroed once per launch
    float* gcnt  = (float*)alloc(NGRAPH * sizeof(float));
    int*   cursor= (int*)  alloc(NTOT * sizeof(int));
    int*   rowptr= (int*)  alloc((NTOT + 1) * sizeof(int));
    int*   esrc  = (int*)  alloc(EDGES * sizeof(int));
    float* ew    = (float*)alloc(EDGES * sizeof(float));
    float* H0    = (float*)alloc((size_t)NTOT * HCH * sizeof(float));
    uint*  U0    = (uint*) alloc((size_t)NTOT * HCH * sizeof(uint));
    uint*  U1    = (uint*) alloc((size_t)NTOT * HCH * sizeof(uint));
    uint*  AGG   = (uint*) alloc((size_t)NTOT * HCH * sizeof(uint));
    ushort* Whi  = (ushort*)alloc(128 * 256 * sizeof(ushort));
    ushort* Wlo  = (ushort*)alloc(128 * 256 * sizeof(ushort));
    float* bprm  = (float*)alloc(NGRAPH * 128 * sizeof(float));
    (void)ws_size; (void)in_sizes; (void)n_in; (void)out_size;

    hipMemsetAsync(d_ws, 0, zero_bytes, stream);
    k_hist   <<<EDGES / 256, 256, 0, stream>>>(dst, deg);
    k_scan   <<<1, 1024, 0, stream>>>(deg, rowptr, cursor);
    k_scatter<<<EDGES / 256, 256, 0, stream>>>(src, dst, L, cursor, esrc, ew);
    k_cnt    <<<NGRAPH, 256, 0, stream>>>(mask, gcnt);
    k_conv1  <<<NTOT / 128, 256, 0, stream>>>(x, W1, b1, H0, U0, sums);

    uint* Ucur = U0; uint* Unext = U1;
    for (int i = 0; i < 15; ++i){
        for (int j = 0; j < 2; ++j){
            int k = 2 * i + j;
            const float* Wk  = Wb + (size_t)k * 256 * HCH;
            const float* bk  = bb + (size_t)k * HCH;
            const float* gk  = gb + (size_t)k * 256;
            const float* bek = betab + (size_t)k * 256;
            float* sk = sums + (size_t)k * 512;
            float* sn = sums + (size_t)(k + 1) * 512;
            bool nextg = (k < 29) && ((((k + 1) / 2) & 1) == 1);
            float* gsn = nextg ? (gsum + (size_t)(k + 1) * NGRAPH * HCH) : nullptr;
            if ((i & 1) == 0){
                k_spmm<<<NTOT / 8, 256, 0, stream>>>(Ucur, rowptr, esrc, ew, AGG, sk);
                k_prep<0><<<9, 256, 0, stream>>>(Wk, bk, gk, bek, sk, nullptr, gcnt, Whi, Wlo, bprm);
                if (j == 0)
                    k_gemm<0,0><<<NTOT / 64, 256, 0, stream>>>(Ucur, AGG, Whi, Wlo, bprm,
                                                               nullptr, nullptr, Unext, sn, mask, gsn);
                else
                    k_gemm<0,1><<<NTOT / 64, 256, 0, stream>>>(Ucur, AGG, Whi, Wlo, bprm,
                                                               H0, H0, Unext, sn, mask, gsn);
            } else {
                float* gs = gsum + (size_t)k * NGRAPH * HCH;
                k_prep<1><<<9, 256, 0, stream>>>(Wk, bk, gk, bek, sk, gs, gcnt, Whi, Wlo, bprm);
                if (j == 0)
                    k_gemm<1,0><<<NTOT / 64, 256, 0, stream>>>(Ucur, nullptr, Whi, Wlo, bprm,
                                                               nullptr, nullptr, Unext, sn, mask, gsn);
                else
                    k_gemm<1,1><<<NTOT / 64, 256, 0, stream>>>(Ucur, nullptr, Whi, Wlo, bprm,
                                                               H0, H0, Unext, sn, mask, gsn);
            }
            uint* tmp = Ucur; Ucur = Unext; Unext = tmp;
        }
    }
    k_final<<<NTOT / 64, 256, 0, stream>>>(Ucur, sums + 30 * 512, g2, beta2, W2, b2, x, (float*)d_out);
}

// Round 4
// 2651.513 us; speedup vs baseline: 1.4247x; 1.4247x over previous
//
#include <hip/hip_runtime.h>
#include <hip/hip_bf16.h>
#include <math.h>

#define NTOT   32768
#define NPER   4096
#define NGRAPH 8
#define EDGES  262144
#define HCH    128
#define EPSBN  1e-5f

typedef short bf16x8 __attribute__((ext_vector_type(8)));
typedef float f32x4  __attribute__((ext_vector_type(4)));

__device__ __forceinline__ float eluf(float x){ return x > 0.f ? x : expm1f(x); }
__device__ __forceinline__ ushort f2bf(float f){
    uint u = __float_as_uint(f);
    u += 0x7fffu + ((u >> 16) & 1u);          // round-to-nearest-even
    return (ushort)(u >> 16);
}
__device__ __forceinline__ float bfhi(uint p){ return __uint_as_float(p & 0xffff0000u); }
__device__ __forceinline__ float bflo(uint p){ return __uint_as_float(p << 16); }
__device__ __forceinline__ uint packu(float v){
    ushort hi = f2bf(v);
    float r = v - __uint_as_float(((uint)hi) << 16);
    ushort lo = f2bf(r);
    return (((uint)hi) << 16) | (uint)lo;
}

// ---------------- CSR build ----------------
__global__ __launch_bounds__(256) void k_hist(const int* __restrict__ dst, int* __restrict__ deg){
    int e = blockIdx.x * 256 + threadIdx.x;
    atomicAdd(&deg[dst[e]], 1);
}

__global__ __launch_bounds__(1024) void k_scan(const int* __restrict__ deg, int* __restrict__ rowptr,
                                               int* __restrict__ cursor){
    __shared__ int part[1024];
    int t = threadIdx.x;
    const int chunk = NTOT / 1024;
    int base = t * chunk;
    int s = 0;
    for (int j = 0; j < chunk; ++j) s += deg[base + j];
    part[t] = s; __syncthreads();
    for (int off = 1; off < 1024; off <<= 1){
        int v = (t >= off) ? part[t - off] : 0;
        __syncthreads();
        part[t] += v;
        __syncthreads();
    }
    int run = part[t] - s;
    for (int j = 0; j < chunk; ++j){
        rowptr[base + j] = run; cursor[base + j] = run;
        run += deg[base + j];
    }
    if (t == 1023) rowptr[NTOT] = run;
}

__global__ __launch_bounds__(256) void k_scatter(const int* __restrict__ src, const int* __restrict__ dst,
                                                 const float* __restrict__ L, int* __restrict__ cursor,
                                                 int* __restrict__ esrc, float* __restrict__ ew){
    int e = blockIdx.x * 256 + threadIdx.x;
    int d = dst[e];
    int pos = atomicAdd(&cursor[d], 1);
    esrc[pos] = src[e];
    ew[pos]   = L[e];
}

// ---------------- per-graph mask count ----------------
__global__ __launch_bounds__(256) void k_cnt(const float* __restrict__ mask, float* __restrict__ gcnt){
    __shared__ float red[4];
    int g = blockIdx.x, t = threadIdx.x;
    float s = 0.f;
    for (int i = t; i < NPER; i += 256) s += mask[g * NPER + i];
    #pragma unroll
    for (int off = 32; off > 0; off >>= 1) s += __shfl_down(s, off);
    if ((t & 63) == 0) red[t >> 6] = s;
    __syncthreads();
    if (t == 0) gcnt[g] = red[0] + red[1] + red[2] + red[3];
}

// ---------------- conv1: H = x@W1+b1 ; Upk = pack(elu(H)) ; stats ----------------
__global__ __launch_bounds__(256) void k_conv1(const float* __restrict__ x, const float* __restrict__ W1,
                                               const float* __restrict__ b1, float* __restrict__ H,
                                               uint* __restrict__ Upk, float* __restrict__ sums0){
    __shared__ float red[2][2][128];
    int t = threadIdx.x, ch = t & 127, pr = t >> 7;
    float w0 = W1[ch], w1 = W1[128 + ch], w2 = W1[256 + ch], bv = b1[ch];
    int base = blockIdx.x * 128;
    float ls = 0.f, lss = 0.f;
    for (int it = 0; it < 64; ++it){
        int row = base + 2 * it + pr;
        const float* xr = x + (size_t)row * 3;
        float h = fmaf(xr[2], w2, fmaf(xr[1], w1, fmaf(xr[0], w0, bv)));
        H[(size_t)row * HCH + ch] = h;
        float u = eluf(h);
        Upk[(size_t)row * HCH + ch] = packu(u);
        ls += u; lss += u * u;
    }
    red[0][pr][ch] = ls; red[1][pr][ch] = lss;
    __syncthreads();
    if (t < 128){
        atomicAdd(&sums0[t],       red[0][0][t] + red[0][1][t]);
        atomicAdd(&sums0[256 + t], red[1][0][t] + red[1][1][t]);
    }
}

// ---------------- SpMM: 2 nodes/thread, 2 acc chains, 4-deep unroll ----------------
__global__ __launch_bounds__(256) void k_spmm(const uint* __restrict__ Upk, const int* __restrict__ rowptr,
                                              const int* __restrict__ esrc, const float* __restrict__ ew,
                                              uint* __restrict__ AGG, float* __restrict__ sums_k){
    __shared__ float red[2][8][128];
    const int t = threadIdx.x;
    const int nl = t >> 5;
    const int c4 = (t & 31) << 2;
    const int bid = blockIdx.x;
    const int sb = ((bid & 7) << 8) | (bid >> 3);   // graph g -> XCD g (2 MB segment per L2)
    const int n0 = sb * 16 + nl;
    const int n1 = n0 + 8;

    float4 a[2];
    #pragma unroll
    for (int q = 0; q < 2; ++q){
        int node = q ? n1 : n0;
        int e0 = rowptr[node], e1 = rowptr[node + 1];
        float4 A = {0,0,0,0}, B = {0,0,0,0};
        int e = e0;
        for (; e + 4 <= e1; e += 4){
            int   s0 = esrc[e],   s1 = esrc[e+1], s2 = esrc[e+2], s3 = esrc[e+3];
            float w0 = ew[e],     w1 = ew[e+1],   w2 = ew[e+2],   w3 = ew[e+3];
            uint4 p0 = *(const uint4*)(Upk + (size_t)s0 * HCH + c4);
            uint4 p1 = *(const uint4*)(Upk + (size_t)s1 * HCH + c4);
            uint4 p2 = *(const uint4*)(Upk + (size_t)s2 * HCH + c4);
            uint4 p3 = *(const uint4*)(Upk + (size_t)s3 * HCH + c4);
            A.x=fmaf(bfhi(p0.x),w0,A.x); A.y=fmaf(bfhi(p0.y),w0,A.y); A.z=fmaf(bfhi(p0.z),w0,A.z); A.w=fmaf(bfhi(p0.w),w0,A.w);
            B.x=fmaf(bfhi(p1.x),w1,B.x); B.y=fmaf(bfhi(p1.y),w1,B.y); B.z=fmaf(bfhi(p1.z),w1,B.z); B.w=fmaf(bfhi(p1.w),w1,B.w);
            A.x=fmaf(bfhi(p2.x),w2,A.x); A.y=fmaf(bfhi(p2.y),w2,A.y); A.z=fmaf(bfhi(p2.z),w2,A.z); A.w=fmaf(bfhi(p2.w),w2,A.w);
            B.x=fmaf(bfhi(p3.x),w3,B.x); B.y=fmaf(bfhi(p3.y),w3,B.y); B.z=fmaf(bfhi(p3.z),w3,B.z); B.w=fmaf(bfhi(p3.w),w3,B.w);
        }
        for (; e < e1; ++e){
            int s0 = esrc[e]; float w0 = ew[e];
            uint4 p0 = *(const uint4*)(Upk + (size_t)s0 * HCH + c4);
            A.x=fmaf(bfhi(p0.x),w0,A.x); A.y=fmaf(bfhi(p0.y),w0,A.y); A.z=fmaf(bfhi(p0.z),w0,A.z); A.w=fmaf(bfhi(p0.w),w0,A.w);
        }
        A.x += B.x; A.y += B.y; A.z += B.z; A.w += B.w;
        a[q] = A;
    }
    uint4 o0, o1;
    o0.x = packu(a[0].x); o0.y = packu(a[0].y); o0.z = packu(a[0].z); o0.w = packu(a[0].w);
    o1.x = packu(a[1].x); o1.y = packu(a[1].y); o1.z = packu(a[1].z); o1.w = packu(a[1].w);
    *(uint4*)(AGG + (size_t)n0 * HCH + c4) = o0;
    *(uint4*)(AGG + (size_t)n1 * HCH + c4) = o1;

    red[0][nl][c4+0]=a[0].x+a[1].x; red[0][nl][c4+1]=a[0].y+a[1].y;
    red[0][nl][c4+2]=a[0].z+a[1].z; red[0][nl][c4+3]=a[0].w+a[1].w;
    red[1][nl][c4+0]=a[0].x*a[0].x+a[1].x*a[1].x; red[1][nl][c4+1]=a[0].y*a[0].y+a[1].y*a[1].y;
    red[1][nl][c4+2]=a[0].z*a[0].z+a[1].z*a[1].z; red[1][nl][c4+3]=a[0].w*a[0].w+a[1].w*a[1].w;
    __syncthreads();
    if (t < 128){
        float s = 0.f, q = 0.f;
        #pragma unroll
        for (int n2 = 0; n2 < 8; ++n2){ s += red[0][n2][t]; q += red[1][n2][t]; }
        atomicAdd(&sums_k[128 + t], s);
        atomicAdd(&sums_k[384 + t], q);
    }
}

// ---------------- weight prep: Bsw = fragment-native swizzled s*W (hi/lo), b' = shift@W + b ----------------
template<int MODE>
__global__ __launch_bounds__(256) void k_prep(
        const float* __restrict__ W, const float* __restrict__ bias,
        const float* __restrict__ gamma, const float* __restrict__ beta,
        const float* __restrict__ sums_k, const float* __restrict__ gsum_k,
        const float* __restrict__ gcnt,
        uint4* __restrict__ Bsw, float* __restrict__ bprm)
{
    constexpr int KC = MODE ? 4 : 8;
    __shared__ float s_s[256], s_sh[256];
    __shared__ float s_avg[NGRAPH * 128];
    const int t = threadIdx.x;
    {
        float m, ex2;
        if (MODE == 1 && t >= 128){
            float S1 = 0.f, S2 = 0.f;
            #pragma unroll
            for (int g = 0; g < NGRAPH; ++g){
                float a = gsum_k[g * 128 + (t - 128)] / gcnt[g];
                s_avg[g * 128 + (t - 128)] = a;
                S1 += a; S2 += a * a;
            }
            m = S1 * (1.f / NGRAPH); ex2 = S2 * (1.f / NGRAPH);
        } else {
            m   = sums_k[t]       * (1.f / NTOT);
            ex2 = sums_k[256 + t] * (1.f / NTOT);
        }
        float var = ex2 - m * m;
        float sc = gamma[t] * rsqrtf(var + EPSBN);
        s_s[t] = sc; s_sh[t] = beta[t] - m * sc;
    }
    __syncthreads();
    if (blockIdx.x < 8){
        const int nt = blockIdx.x;
        for (int it = t; it < KC * 64; it += 256){
            int kc = it >> 6, l = it & 63;
            int col = nt * 16 + (l & 15);
            int k0  = kc * 32 + (l >> 4) * 8;
            ushort hi[8], lo[8];
            #pragma unroll
            for (int q = 0; q < 8; ++q){
                int k = k0 + q;
                float v = W[(size_t)k * 128 + col] * s_s[k];
                ushort h = f2bf(v);
                hi[q] = h;
                lo[q] = f2bf(v - __uint_as_float(((uint)h) << 16));
            }
            uint4 vh, vl;
            vh.x = hi[0] | ((uint)hi[1] << 16); vh.y = hi[2] | ((uint)hi[3] << 16);
            vh.z = hi[4] | ((uint)hi[5] << 16); vh.w = hi[6] | ((uint)hi[7] << 16);
            vl.x = lo[0] | ((uint)lo[1] << 16); vl.y = lo[2] | ((uint)lo[3] << 16);
            vl.z = lo[4] | ((uint)lo[5] << 16); vl.w = lo[6] | ((uint)lo[7] << 16);
            Bsw[(size_t)((nt * KC + kc) * 2 + 0) * 64 + l] = vh;
            Bsw[(size_t)((nt * KC + kc) * 2 + 1) * 64 + l] = vl;
        }
    } else if (t < 128){
        const int n = t;
        float acc = bias[n];
        if (MODE == 0){
            for (int c = 0; c < 256; ++c) acc = fmaf(s_sh[c], W[(size_t)c * 128 + n], acc);
            bprm[n] = acc;
        } else {
            for (int c = 0; c < 128; ++c) acc = fmaf(s_sh[c], W[(size_t)c * 128 + n], acc);
            for (int g = 0; g < NGRAPH; ++g){
                float bg = acc;
                for (int c = 0; c < 128; ++c)
                    bg = fmaf(fmaf(s_avg[g * 128 + c], s_s[128 + c], s_sh[128 + c]),
                              W[(size_t)(128 + c) * 128 + n], bg);
                bprm[g * 128 + n] = bg;
            }
        }
    }
}

// ---------------- MFMA GEMM: LDS-staged A (XOR swizzle) x fragment-native B ----------------
template<int MODE, int RES>
__global__ __launch_bounds__(256) void k_gemm(
        const uint* __restrict__ Upk, const uint* __restrict__ AGG,
        const uint4* __restrict__ Bsw, const float* __restrict__ bprm,
        const float* __restrict__ Hres, float* __restrict__ Hout,
        uint* __restrict__ Uout, float* __restrict__ sums_n,
        const float* __restrict__ mask, float* __restrict__ gsum_next)
{
    constexpr int KC = (MODE == 0) ? 8 : 4;
    __shared__ uint a_sm[2][64][32];          // 2 x 8 KB, chunk-swizzled
    __shared__ float red[2][16][128];
    const int t = threadIdx.x;
    const int w = t >> 6, lane = t & 63;
    const int rlo = lane & 15, kg = lane >> 4;
    const int bid = blockIdx.x;
    const int sb  = ((bid & 7) << 6) | (bid >> 3);   // graph g -> XCD g
    const int row0 = sb * 64;

    auto stage = [&](int kc, int b){
        #pragma unroll
        for (int i = 0; i < 2; ++i){
            int idx = t + 256 * i;
            int row = idx >> 3, sl = idx & 7;
            const uint* sp = (MODE == 0 && kc >= 4)
                ? (AGG + (size_t)(row0 + row) * HCH + (kc - 4) * 32 + sl * 4)
                : (Upk + (size_t)(row0 + row) * HCH + kc * 32 + sl * 4);
            uint4 v = *(const uint4*)sp;
            *(uint4*)&a_sm[b][row][(sl ^ (row & 7)) * 4] = v;
        }
    };

    f32x4 acc[8];
    #pragma unroll
    for (int n = 0; n < 8; ++n) acc[n] = (f32x4){0.f, 0.f, 0.f, 0.f};

    stage(0, 0);
    __syncthreads();
    for (int kc = 0; kc < KC; ++kc){
        if (kc + 1 < KC) stage(kc + 1, (kc + 1) & 1);
        const int rr = w * 16 + rlo;
        uint4 c0 = *(const uint4*)&a_sm[kc & 1][rr][((2 * kg)     ^ (rr & 7)) * 4];
        uint4 c1 = *(const uint4*)&a_sm[kc & 1][rr][((2 * kg + 1) ^ (rr & 7)) * 4];
        union { uint u[4]; bf16x8 v; } ah, al;
        ah.u[0] = (c0.x >> 16) | (c0.y & 0xffff0000u);
        ah.u[1] = (c0.z >> 16) | (c0.w & 0xffff0000u);
        ah.u[2] = (c1.x >> 16) | (c1.y & 0xffff0000u);
        ah.u[3] = (c1.z >> 16) | (c1.w & 0xffff0000u);
        al.u[0] = (c0.x & 0xffffu) | (c0.y << 16);
        al.u[1] = (c0.z & 0xffffu) | (c0.w << 16);
        al.u[2] = (c1.x & 0xffffu) | (c1.y << 16);
        al.u[3] = (c1.z & 0xffffu) | (c1.w << 16);
        #pragma unroll
        for (int n = 0; n < 8; ++n){
            union { uint4 q; bf16x8 v; } bh, bl;
            bh.q = Bsw[(size_t)((n * KC + kc) * 2 + 0) * 64 + lane];
            bl.q = Bsw[(size_t)((n * KC + kc) * 2 + 1) * 64 + lane];
            acc[n] = __builtin_amdgcn_mfma_f32_16x16x32_bf16(ah.v, bh.v, acc[n], 0, 0, 0);
            acc[n] = __builtin_amdgcn_mfma_f32_16x16x32_bf16(ah.v, bl.v, acc[n], 0, 0, 0);
            acc[n] = __builtin_amdgcn_mfma_f32_16x16x32_bf16(al.v, bh.v, acc[n], 0, 0, 0);
        }
        __syncthreads();
    }

    // epilogue: bias (+res) -> h ; u = elu(h) ; pack ; stats (+ masked per-graph sums)
    const float* bp = (MODE == 1) ? (bprm + (row0 >> 12) * 128) : bprm;
    const int r0 = row0 + w * 16 + kg * 4;
    float mk0 = 0.f, mk1 = 0.f, mk2 = 0.f, mk3 = 0.f;
    if (gsum_next){ mk0 = mask[r0]; mk1 = mask[r0+1]; mk2 = mask[r0+2]; mk3 = mask[r0+3]; }
    float sN[8], qN[8], gN[8];
    #pragma unroll
    for (int n = 0; n < 8; ++n){
        const int c = n * 16 + rlo;
        const float bc = bp[c];
        float s = 0.f, q = 0.f, g = 0.f;
        #pragma unroll
        for (int r = 0; r < 4; ++r){
            int row = r0 + r;
            float h = acc[n][r] + bc;
            if (RES){
                h += Hres[(size_t)row * HCH + c];
                Hout[(size_t)row * HCH + c] = h;
            }
            float u = eluf(h);
            Uout[(size_t)row * HCH + c] = packu(u);
            s += u; q += u * u;
            if (gsum_next){
                float mkr = (r == 0) ? mk0 : (r == 1) ? mk1 : (r == 2) ? mk2 : mk3;
                g = fmaf(u, mkr, g);
            }
        }
        sN[n] = s; qN[n] = q; gN[n] = g;
    }
    const int slot = w * 4 + kg;
    #pragma unroll
    for (int n = 0; n < 8; ++n){
        red[0][slot][n * 16 + rlo] = sN[n];
        red[1][slot][n * 16 + rlo] = qN[n];
    }
    __syncthreads();
    if (t < 128){
        float a = 0.f, b = 0.f;
        #pragma unroll
        for (int q = 0; q < 16; ++q){ a += red[0][q][t]; b += red[1][q][t]; }
        atomicAdd(&sums_n[t], a);
        atomicAdd(&sums_n[256 + t], b);
    }
    if (gsum_next){
        __syncthreads();
        #pragma unroll
        for (int n = 0; n < 8; ++n) red[0][slot][n * 16 + rlo] = gN[n];
        __syncthreads();
        if (t < 128){
            float a = 0.f;
            #pragma unroll
            for (int q = 0; q < 16; ++q) a += red[0][q][t];
            atomicAdd(&gsum_next[(row0 >> 12) * 128 + t], a);
        }
    }
}

// ---------------- final: BN(elu(h)) @ W2 + b2 + x[:, :1] ----------------
__global__ __launch_bounds__(256) void k_final(const uint* __restrict__ Upk, const float* __restrict__ sums30,
                                               const float* __restrict__ g2, const float* __restrict__ beta2,
                                               const float* __restrict__ W2, const float* __restrict__ b2,
                                               const float* __restrict__ x, float* __restrict__ out){
    __shared__ float s_s[128], s_sh[128];
    __shared__ float wred[4];
    int t = threadIdx.x;
    if (t < 128){
        float m   = sums30[t]       * (1.f / NTOT);
        float ex2 = sums30[256 + t] * (1.f / NTOT);
        float var = ex2 - m * m;
        float sc = g2[t] * rsqrtf(var + EPSBN);
        s_s[t] = sc; s_sh[t] = beta2[t] - m * sc;
    }
    __syncthreads();
    int lane = t & 63, wid = t >> 6;
    int ch = t & 127, pr = t >> 7;
    float w2 = W2[ch];
    float b2v = b2[0];
    int base = blockIdx.x * 64;
    for (int it = 0; it < 32; ++it){
        int rowa = base + it * 2;
        int row  = rowa + pr;
        uint p = Upk[(size_t)row * HCH + ch];
        float u = bfhi(p) + bflo(p);
        float v = (u * s_s[ch] + s_sh[ch]) * w2;
        #pragma unroll
        for (int off = 32; off > 0; off >>= 1) v += __shfl_down(v, off);
        if (lane == 0) wred[wid] = v;
        __syncthreads();
        if (t == 0)   out[rowa]     = wred[0] + wred[1] + b2v + x[(size_t)rowa * 3];
        if (t == 128) out[rowa + 1] = wred[2] + wred[3] + b2v + x[(size_t)(rowa + 1) * 3];
        __syncthreads();
    }
}

// ---------------- host ----------------
extern "C" void kernel_launch(void* const* d_in, const int* in_sizes, int n_in,
                              void* d_out, int out_size, void* d_ws, size_t ws_size,
                              hipStream_t stream){
    const float* x    = (const float*)d_in[0];
    const float* L    = (const float*)d_in[1];
    const float* mask = (const float*)d_in[2];
    const float* W1   = (const float*)d_in[3];
    const float* b1   = (const float*)d_in[4];
    const float* Wb   = (const float*)d_in[5];
    const float* bb   = (const float*)d_in[6];
    const float* gb   = (const float*)d_in[7];
    const float* betab= (const float*)d_in[8];
    const float* g2   = (const float*)d_in[9];
    const float* beta2= (const float*)d_in[10];
    const float* W2   = (const float*)d_in[11];
    const float* b2   = (const float*)d_in[12];
    const int*   src  = (const int*)d_in[13];
    const int*   dst  = (const int*)d_in[14];

    char* base = (char*)d_ws;
    size_t off = 0;
    auto alloc = [&](size_t bytes)->char*{
        char* r = base + off;
        off = (off + bytes + 255) & ~(size_t)255;
        return r;
    };
    float* sums  = (float*)alloc(31 * 512 * sizeof(float));
    float* gsum  = (float*)alloc(30 * NGRAPH * HCH * sizeof(float));
    int*   deg   = (int*)  alloc(NTOT * sizeof(int));
    size_t zero_bytes = off;                                       // zeroed once per launch
    float* gcnt  = (float*)alloc(NGRAPH * sizeof(float));
    int*   cursor= (int*)  alloc(NTOT * sizeof(int));
    int*   rowptr= (int*)  alloc((NTOT + 1) * sizeof(int));
    int*   esrc  = (int*)  alloc(EDGES * sizeof(int));
    float* ew    = (float*)alloc(EDGES * sizeof(float));
    float* H0    = (float*)alloc((size_t)NTOT * HCH * sizeof(float));
    uint*  U0    = (uint*) alloc((size_t)NTOT * HCH * sizeof(uint));
    uint*  U1    = (uint*) alloc((size_t)NTOT * HCH * sizeof(uint));
    uint*  AGG   = (uint*) alloc((size_t)NTOT * HCH * sizeof(uint));
    uint4* Bsw   = (uint4*)alloc(8192 * sizeof(uint4));            // 128 KB fragment-native W'
    float* bprm  = (float*)alloc(NGRAPH * 128 * sizeof(float));
    (void)ws_size; (void)in_sizes; (void)n_in; (void)out_size;

    hipMemsetAsync(d_ws, 0, zero_bytes, stream);
    k_hist   <<<EDGES / 256, 256, 0, stream>>>(dst, deg);
    k_scan   <<<1, 1024, 0, stream>>>(deg, rowptr, cursor);
    k_scatter<<<EDGES / 256, 256, 0, stream>>>(src, dst, L, cursor, esrc, ew);
    k_cnt    <<<NGRAPH, 256, 0, stream>>>(mask, gcnt);
    k_conv1  <<<NTOT / 128, 256, 0, stream>>>(x, W1, b1, H0, U0, sums);

    uint* Ucur = U0; uint* Unext = U1;
    for (int i = 0; i < 15; ++i){
        for (int j = 0; j < 2; ++j){
            int k = 2 * i + j;
            const float* Wk  = Wb + (size_t)k * 256 * HCH;
            const float* bk  = bb + (size_t)k * HCH;
            const float* gk  = gb + (size_t)k * 256;
            const float* bek = betab + (size_t)k * 256;
            float* sk = sums + (size_t)k * 512;
            float* sn = sums + (size_t)(k + 1) * 512;
            bool nextg = (k < 29) && ((((k + 1) / 2) & 1) == 1);
            float* gsn = nextg ? (gsum + (size_t)(k + 1) * NGRAPH * HCH) : nullptr;
            if ((i & 1) == 0){
                k_spmm<<<NTOT / 16, 256, 0, stream>>>(Ucur, rowptr, esrc, ew, AGG, sk);
                k_prep<0><<<9, 256, 0, stream>>>(Wk, bk, gk, bek, sk, nullptr, gcnt, Bsw, bprm);
                if (j == 0)
                    k_gemm<0,0><<<NTOT / 64, 256, 0, stream>>>(Ucur, AGG, Bsw, bprm,
                                                               nullptr, nullptr, Unext, sn, mask, gsn);
                else
                    k_gemm<0,1><<<NTOT / 64, 256, 0, stream>>>(Ucur, AGG, Bsw, bprm,
                                                               H0, H0, Unext, sn, mask, gsn);
            } else {
                float* gs = gsum + (size_t)k * NGRAPH * HCH;
                k_prep<1><<<9, 256, 0, stream>>>(Wk, bk, gk, bek, sk, gs, gcnt, Bsw, bprm);
                if (j == 0)
                    k_gemm<1,0><<<NTOT / 64, 256, 0, stream>>>(Ucur, nullptr, Bsw, bprm,
                                                               nullptr, nullptr, Unext, sn, mask, gsn);
                else
                    k_gemm<1,1><<<NTOT / 64, 256, 0, stream>>>(Ucur, nullptr, Bsw, bprm,
                                                               H0, H0, Unext, sn, mask, gsn);
            }
            uint* tmp = Ucur; Ucur = Unext; Unext = tmp;
        }
    }
    k_final<<<NTOT / 64, 256, 0, stream>>>(Ucur, sums + 30 * 512, g2, beta2, W2, b2, x, (float*)d_out);
}